// Round 4
// baseline (270.547 us; speedup 1.0000x reference)
//
#include <hip/hip_runtime.h>

typedef __attribute__((ext_vector_type(8))) short bhalf8;
typedef __attribute__((ext_vector_type(4))) float floatx4;

#define ALPHA_LR 0.2f

__device__ __forceinline__ unsigned short f2bf(float f) {
  union { float f; unsigned int u; } v; v.f = f;
  unsigned int r = v.u + 0x7fffu + ((v.u >> 16) & 1u);
  return (unsigned short)(r >> 16);
}
__device__ __forceinline__ float bf2f(unsigned short u) {
  union { unsigned int u; float f; } v; v.u = ((unsigned int)u) << 16;
  return v.f;
}
// async global->LDS, 16B per lane; lds ptr must be wave-uniform (HW adds lane*16)
__device__ __forceinline__ void gld16(const void* g, void* l) {
  __builtin_amdgcn_global_load_lds((const __attribute__((address_space(1))) unsigned int*)g,
                                   (__attribute__((address_space(3))) unsigned int*)l,
                                   16, 0, 0);
}

// ---------------------------------------------------------------------------
// k0w: W [k][n] fp32 -> WT_hi/WT_lo bf16, k-tiled layout [ks=8][n=256][k'=32]
// ---------------------------------------------------------------------------
__global__ void k0w_split(const float* __restrict__ W,
                          unsigned short* __restrict__ WThi,
                          unsigned short* __restrict__ WTlo) {
  __shared__ float s[16][17];
  const int tx = threadIdx.x, ty = threadIdx.y;
  const int n0 = blockIdx.x * 16, k0 = blockIdx.y * 16;
  s[ty][tx] = W[(k0 + ty) * 256 + n0 + tx];
  __syncthreads();
  float v = s[tx][ty];  // = W[k0+tx][n0+ty]
  const int k = k0 + tx, n = n0 + ty;
  unsigned short hi = f2bf(v);
  unsigned short lo = f2bf(v - bf2f(hi));
  const int idx = (k >> 5) * 8192 + n * 32 + (k & 31);
  WThi[idx] = hi;
  WTlo[idx] = lo;
}

// ---------------------------------------------------------------------------
// k1: Wh = h @ W via split-bf16 MFMA (hi*hi + hi*lo + lo*hi), h split in-kernel.
// Writes WhPack bf16 [B][jt=64][f=256][j'=32] and s1/s2 (fp32 dots with a).
// ---------------------------------------------------------------------------
__global__ __launch_bounds__(512, 2) void k1_mfma(const float* __restrict__ h,
                                                  const unsigned short* __restrict__ Bhi_g,
                                                  const unsigned short* __restrict__ Blo_g,
                                                  const float* __restrict__ a_g,
                                                  unsigned short* __restrict__ WhPack,
                                                  float* __restrict__ s1,
                                                  float* __restrict__ s2) {
  __shared__ unsigned short Ah[64 * 264], Al[64 * 264];  // 33 KB each
  __shared__ unsigned short Bh[2][8192], Bl[2][8192];    // 16 KB per buffer
  __shared__ float s1red[64], s2red[64];
  const int t = threadIdx.x;
  const long r0 = (long)blockIdx.x * 64;
  const int wave = t >> 6, lane = t & 63;

  if (t < 64) { s1red[t] = 0.f; s2red[t] = 0.f; }

#pragma unroll
  for (int rep = 0; rep < 2; rep++) {
    const int off = wave * 1024 + rep * 512;
    gld16(Bhi_g + off + lane * 8, &Bh[0][off]);
    gld16(Blo_g + off + lane * 8, &Bl[0][off]);
  }

#pragma unroll
  for (int q = 0; q < 8; q++) {
    int idx = q * 512 + t;
    int row = idx >> 6, c4 = idx & 63;
    float4 x = *(const float4*)(h + (r0 + row) * 256 + c4 * 4);
    float xs[4] = {x.x, x.y, x.z, x.w};
    unsigned short hs[4], ls[4];
#pragma unroll
    for (int qq = 0; qq < 4; qq++) {
      hs[qq] = f2bf(xs[qq]);
      ls[qq] = f2bf(xs[qq] - bf2f(hs[qq]));
    }
    *(ushort4*)&Ah[row * 264 + c4 * 4] = (ushort4){hs[0], hs[1], hs[2], hs[3]};
    *(ushort4*)&Al[row * 264 + c4 * 4] = (ushort4){ls[0], ls[1], ls[2], ls[3]};
  }
  __syncthreads();

  const int wm = wave >> 2, wn = wave & 3;
  const int lhi = lane >> 4, llo = lane & 15;

  floatx4 acc[2][4];
#pragma unroll
  for (int mt = 0; mt < 2; mt++)
#pragma unroll
    for (int nt = 0; nt < 4; nt++) acc[mt][nt] = (floatx4){0.f, 0.f, 0.f, 0.f};

  for (int ks = 0; ks < 8; ks++) {
    const int cur = ks & 1, nxt = cur ^ 1, ksn = (ks + 1) & 7;
#pragma unroll
    for (int rep = 0; rep < 2; rep++) {
      const int off = wave * 1024 + rep * 512;
      gld16(Bhi_g + ksn * 8192 + off + lane * 8, &Bh[nxt][off]);
      gld16(Blo_g + ksn * 8192 + off + lane * 8, &Bl[nxt][off]);
    }

    const int k0 = ks * 32;
    bhalf8 ah[2], al[2], bh[4], bl[4];
#pragma unroll
    for (int mt = 0; mt < 2; mt++) {
      int ro = (wm * 32 + mt * 16 + llo) * 264 + k0 + lhi * 8;
      ah[mt] = *(const bhalf8*)&Ah[ro];
      al[mt] = *(const bhalf8*)&Al[ro];
    }
#pragma unroll
    for (int nt = 0; nt < 4; nt++) {
      int ro = (wn * 64 + nt * 16 + llo) * 32 + lhi * 8;
      bh[nt] = *(const bhalf8*)&Bh[cur][ro];
      bl[nt] = *(const bhalf8*)&Bl[cur][ro];
    }
#pragma unroll
    for (int mt = 0; mt < 2; mt++)
#pragma unroll
      for (int nt = 0; nt < 4; nt++) {
        acc[mt][nt] = __builtin_amdgcn_mfma_f32_16x16x32_bf16(ah[mt], bh[nt], acc[mt][nt], 0, 0, 0);
        acc[mt][nt] = __builtin_amdgcn_mfma_f32_16x16x32_bf16(ah[mt], bl[nt], acc[mt][nt], 0, 0, 0);
        acc[mt][nt] = __builtin_amdgcn_mfma_f32_16x16x32_bf16(al[mt], bh[nt], acc[mt][nt], 0, 0, 0);
      }
    __syncthreads();
  }

  float a1v[4], a2v[4];
#pragma unroll
  for (int nt = 0; nt < 4; nt++) {
    int f = wn * 64 + nt * 16 + llo;
    a1v[nt] = a_g[f];
    a2v[nt] = a_g[256 + f];
  }

  const int b = (int)(r0 >> 11);
  const int jt_base = (int)((r0 & 2047) >> 5);

#pragma unroll
  for (int mt = 0; mt < 2; mt++) {
    float p1[4], p2[4];
#pragma unroll
    for (int reg = 0; reg < 4; reg++) {
      p1[reg] = acc[mt][0][reg] * a1v[0] + acc[mt][1][reg] * a1v[1] +
                acc[mt][2][reg] * a1v[2] + acc[mt][3][reg] * a1v[3];
      p2[reg] = acc[mt][0][reg] * a2v[0] + acc[mt][1][reg] * a2v[1] +
                acc[mt][2][reg] * a2v[2] + acc[mt][3][reg] * a2v[3];
    }
#pragma unroll
    for (int off = 1; off < 16; off <<= 1) {
#pragma unroll
      for (int reg = 0; reg < 4; reg++) {
        p1[reg] += __shfl_xor(p1[reg], off);
        p2[reg] += __shfl_xor(p2[reg], off);
      }
    }
    if (llo == 0) {
#pragma unroll
      for (int reg = 0; reg < 4; reg++) {
        int il = wm * 32 + mt * 16 + lhi * 4 + reg;
        atomicAdd(&s1red[il], p1[reg]);
        atomicAdd(&s2red[il], p2[reg]);
      }
    }
#pragma unroll
    for (int nt = 0; nt < 4; nt++) {
      int f = wn * 64 + nt * 16 + llo;
      int jt = jt_base + wm;
      ushort4 pk = (ushort4){f2bf(acc[mt][nt][0]), f2bf(acc[mt][nt][1]),
                             f2bf(acc[mt][nt][2]), f2bf(acc[mt][nt][3])};
      *(ushort4*)&WhPack[((long)((b * 64 + jt) * 256 + f)) * 32 + mt * 16 + lhi * 4] = pk;
    }
  }

  __syncthreads();
  if (t < 64) {
    s1[r0 + t] = s1red[t];
    s2[r0 + t] = s2red[t];
  }
}

// ---------------------------------------------------------------------------
// K2: per row: M, linv, and adj bit-pack (unchanged)
// ---------------------------------------------------------------------------
__global__ __launch_bounds__(256) void k2_stats(const int* __restrict__ adj,
                                                const float* __restrict__ s1,
                                                const float* __restrict__ s2,
                                                float* __restrict__ Mv,
                                                float* __restrict__ linv,
                                                unsigned int* __restrict__ packed) {
  const int t = threadIdx.x;
  const long r = blockIdx.x;
  const int b = (int)(r >> 11);
  __shared__ float red[4];
  __shared__ int redi[4];
  __shared__ unsigned char bytes[256];

  const int4* arow = (const int4*)(adj + r * 2048);
  int4 a0 = arow[t * 2], a1 = arow[t * 2 + 1];
  unsigned int m8 = (unsigned)(a0.x > 0) | ((unsigned)(a0.y > 0) << 1) |
                    ((unsigned)(a0.z > 0) << 2) | ((unsigned)(a0.w > 0) << 3) |
                    ((unsigned)(a1.x > 0) << 4) | ((unsigned)(a1.y > 0) << 5) |
                    ((unsigned)(a1.z > 0) << 6) | ((unsigned)(a1.w > 0) << 7);

  int cnt = __popc(m8);
  for (int o = 32; o; o >>= 1) cnt += __shfl_xor(cnt, o);
  if ((t & 63) == 0) redi[t >> 6] = cnt;
  __syncthreads();
  int total = redi[0] + redi[1] + redi[2] + redi[3];
  if (total == 0) m8 = 0xFFu;

  const float4* s2p = (const float4*)(s2 + (long)b * 2048);
  float4 v0 = s2p[t * 2], v1 = s2p[t * 2 + 1];
  float sv[8] = {v0.x, v0.y, v0.z, v0.w, v1.x, v1.y, v1.z, v1.w};

  float mx = -INFINITY;
#pragma unroll
  for (int q = 0; q < 8; q++)
    if ((m8 >> q) & 1) mx = fmaxf(mx, sv[q]);
  for (int o = 32; o; o >>= 1) mx = fmaxf(mx, __shfl_xor(mx, o));
  if ((t & 63) == 0) red[t >> 6] = mx;
  __syncthreads();
  mx = fmaxf(fmaxf(red[0], red[1]), fmaxf(red[2], red[3]));

  const float s1i = s1[r];
  const float xm = s1i + mx;
  const float M = fmaxf(xm, ALPHA_LR * xm);

  float lsum = 0.f;
#pragma unroll
  for (int q = 0; q < 8; q++) {
    if ((m8 >> q) & 1) {
      float x = s1i + sv[q];
      float le = fmaxf(x, ALPHA_LR * x);
      lsum += __expf(le - M);
    }
  }
  for (int o = 32; o; o >>= 1) lsum += __shfl_xor(lsum, o);
  __syncthreads();
  if ((t & 63) == 0) red[t >> 6] = lsum;
  __syncthreads();
  lsum = red[0] + red[1] + red[2] + red[3];

  if (t == 0) { Mv[r] = M; linv[r] = 1.f / lsum; }

  bytes[t] = (unsigned char)m8;
  __syncthreads();
  if (t < 64) {
    unsigned int w = (unsigned)bytes[t * 4] | ((unsigned)bytes[t * 4 + 1] << 8) |
                     ((unsigned)bytes[t * 4 + 2] << 16) | ((unsigned)bytes[t * 4 + 3] << 24);
    packed[r * 64 + t] = w;
  }
}

// ---------------------------------------------------------------------------
// K3 v2: out = elu( (P @ Wh) * linv ). BARRIER-FREE main loop.
// A (P) built directly in MFMA A-fragment registers (lane row = lane&15 fixed
// -> s1/M are loop-invariant per-lane scalars; 8 exps per frag in-register).
// B loaded straight global->VGPR fragments (dense 1KB per instr, L2-hot),
// register double-buffered. LDS only for s2 / adj-bits / linv (staged once).
// grid (4 f-chunks, 16 row-tiles, 8 b) x 256 thr; wave tile 32 rows x 64 f.
// ---------------------------------------------------------------------------
__global__ __launch_bounds__(256, 3) void k3_attn(const unsigned short* __restrict__ WhPack,
                                                  const unsigned int* __restrict__ packed,
                                                  const float* __restrict__ s1g,
                                                  const float* __restrict__ s2g,
                                                  const float* __restrict__ Mg,
                                                  const float* __restrict__ lg,
                                                  float* __restrict__ out) {
  const int t = threadIdx.x;
  const int fc = blockIdx.x;  // f-chunk (64 cols)
  const int ry = blockIdx.y;  // row-tile (128 rows)
  const int b = blockIdx.z;
  const int rowbase = ry * 128;

  __shared__ float s2all[2048];          // 8 KB
  __shared__ unsigned int bits[128 * 68];  // [row][jt] pad 64->68, 34.8 KB
  __shared__ float lvv[128];

  {  // stage s2
    const float4* src = (const float4*)(s2g + (long)b * 2048);
    float4* dst = (float4*)s2all;
    dst[t] = src[t];
    dst[256 + t] = src[256 + t];
  }
  {  // stage bits: 128 rows x 64 u32, contiguous in global
    const int4* src = (const int4*)(packed + ((long)b * 2048 + rowbase) * 64);
#pragma unroll
    for (int q = 0; q < 8; q++) {
      int idx = q * 256 + t;
      int row = idx >> 4, c = idx & 15;
      int4 v = src[idx];
      *(int4*)&bits[row * 68 + c * 4] = v;
    }
  }
  if (t < 128) lvv[t] = lg[(long)b * 2048 + rowbase + t];

  const int wave = t >> 6, lane = t & 63;
  const int lhi = lane >> 4, llo = lane & 15;
  const int wrow = wave * 32;  // block-local row base for this wave

  // loop-invariant per-lane row scalars (A row = mt*16 + llo)
  float s1i[2], Mi[2];
#pragma unroll
  for (int mt = 0; mt < 2; mt++) {
    long r = (long)b * 2048 + rowbase + wrow + mt * 16 + llo;
    s1i[mt] = s1g[r];
    Mi[mt] = Mg[r];
  }
  __syncthreads();  // the only block barrier

  // per-lane global B pointer: frag(jt,nt) at Bl + jt*8192 + nt*512
  const unsigned short* Bl = WhPack + (long)b * 64 * 8192 + fc * 64 * 32 + llo * 32 + lhi * 8;

  floatx4 acc[2][4];
#pragma unroll
  for (int mt = 0; mt < 2; mt++)
#pragma unroll
    for (int nt = 0; nt < 4; nt++) acc[mt][nt] = (floatx4){0.f, 0.f, 0.f, 0.f};

  bhalf8 B0[4], B1[4];
#pragma unroll
  for (int nt = 0; nt < 4; nt++) B0[nt] = *(const bhalf8*)(Bl + nt * 512);

#define K3_STEP(JT, BUF)                                                        \
  {                                                                             \
    const int jt_ = (JT);                                                       \
    float4 s2lo = *(const float4*)&s2all[jt_ * 32 + lhi * 8];                   \
    float4 s2hi = *(const float4*)&s2all[jt_ * 32 + lhi * 8 + 4];               \
    float s2v[8] = {s2lo.x, s2lo.y, s2lo.z, s2lo.w,                             \
                    s2hi.x, s2hi.y, s2hi.z, s2hi.w};                            \
    bhalf8 afr[2];                                                              \
    _Pragma("unroll") for (int mt = 0; mt < 2; mt++) {                          \
      unsigned int wv = bits[(wrow + mt * 16 + llo) * 68 + jt_];                \
      union { unsigned int u[4]; bhalf8 v; } au;                                \
      _Pragma("unroll") for (int pp = 0; pp < 4; pp++) {                        \
        float x0 = ((wv >> (lhi * 8 + 2 * pp)) & 1u) ? (s1i[mt] + s2v[2 * pp])  \
                                                     : -1e30f;                  \
        float x1 = ((wv >> (lhi * 8 + 2 * pp + 1)) & 1u)                        \
                       ? (s1i[mt] + s2v[2 * pp + 1]) : -1e30f;                  \
        x0 = fmaxf(x0, ALPHA_LR * x0);                                          \
        x1 = fmaxf(x1, ALPHA_LR * x1);                                          \
        union { float f; unsigned int u; } u0, u1;                              \
        u0.f = __expf(x0 - Mi[mt]);                                             \
        u1.f = __expf(x1 - Mi[mt]);                                             \
        au.u[pp] = (u0.u >> 16) | (u1.u & 0xffff0000u);                         \
      }                                                                         \
      afr[mt] = au.v;                                                           \
    }                                                                           \
    _Pragma("unroll") for (int mt = 0; mt < 2; mt++)                            \
        _Pragma("unroll") for (int nt = 0; nt < 4; nt++)                        \
            acc[mt][nt] = __builtin_amdgcn_mfma_f32_16x16x32_bf16(              \
                afr[mt], BUF[nt], acc[mt][nt], 0, 0, 0);                        \
  }

  for (int jt = 0; jt < 64; jt += 2) {
    const unsigned short* p1 = Bl + (jt + 1) * 8192;
#pragma unroll
    for (int nt = 0; nt < 4; nt++) B1[nt] = *(const bhalf8*)(p1 + nt * 512);
    K3_STEP(jt, B0)
    const int jn = (jt + 2 < 64) ? jt + 2 : 63;
    const unsigned short* p0 = Bl + jn * 8192;
#pragma unroll
    for (int nt = 0; nt < 4; nt++) B0[nt] = *(const bhalf8*)(p0 + nt * 512);
    K3_STEP(jt + 1, B1)
  }
#undef K3_STEP

  // epilogue: C/D row = lhi*4+reg, col = llo
#pragma unroll
  for (int mt = 0; mt < 2; mt++) {
#pragma unroll
    for (int nt = 0; nt < 4; nt++) {
#pragma unroll
      for (int reg = 0; reg < 4; reg++) {
        int brow = wrow + mt * 16 + lhi * 4 + reg;
        float v = acc[mt][nt][reg] * lvv[brow];
        v = v > 0.f ? v : expm1f(v);
        out[((long)b * 2048 + rowbase + brow) * 256 + fc * 64 + nt * 16 + llo] = v;
      }
    }
  }
}

// ---------------------------------------------------------------------------
extern "C" void kernel_launch(void* const* d_in, const int* in_sizes, int n_in,
                              void* d_out, int out_size, void* d_ws, size_t ws_size,
                              hipStream_t stream) {
  const float* h = (const float*)d_in[0];
  const int* adj = (const int*)d_in[1];
  const float* W = (const float*)d_in[2];
  const float* a = (const float*)d_in[3];
  float* out = (float*)d_out;

  char* ws = (char*)d_ws;
  unsigned short* WhPack = (unsigned short*)ws;            //  8,388,608 B
  unsigned int* packed = (unsigned int*)(ws + 8388608);    //  4,194,304 B
  unsigned short* WThi = (unsigned short*)(ws + 12582912); //    131,072 B
  unsigned short* WTlo = (unsigned short*)(ws + 12713984); //    131,072 B
  float* s1 = (float*)(ws + 12845056);                     //     65,536 B
  float* s2 = (float*)(ws + 12910592);                     //     65,536 B
  float* Mv = (float*)(ws + 12976128);                     //     65,536 B
  float* linv = (float*)(ws + 13041664);                   //     65,536 B

  hipLaunchKernelGGL(k0w_split, dim3(16, 16), dim3(16, 16), 0, stream, W, WThi, WTlo);
  hipLaunchKernelGGL(k1_mfma, dim3(256), dim3(512), 0, stream, h, WThi, WTlo, a,
                     WhPack, s1, s2);
  hipLaunchKernelGGL(k2_stats, dim3(16384), dim3(256), 0, stream, adj, s1, s2, Mv, linv, packed);
  hipLaunchKernelGGL(k3_attn, dim3(4, 16, 8), dim3(256), 0, stream, WhPack, packed,
                     s1, s2, Mv, linv, out);
}